// Round 1
// baseline (4147.823 us; speedup 1.0000x reference)
//
#include <hip/hip_runtime.h>

static inline int cdiv(int a, int b) { return (a + b - 1) / b; }

// ---------------- degree / dinv ----------------

__global__ void init_deg_kernel(float* __restrict__ deg, int n) {
    int i = blockIdx.x * blockDim.x + threadIdx.x;
    if (i < n) deg[i] = 1.0f;  // self-loop
}

__global__ void accum_deg_kernel(const int* __restrict__ dst, float* __restrict__ deg, int ne) {
    int e = blockIdx.x * blockDim.x + threadIdx.x;
    if (e < ne) atomicAdd(&deg[dst[e]], 1.0f);
}

__global__ void dinv_kernel(float* __restrict__ deg, int n) {
    int i = blockIdx.x * blockDim.x + threadIdx.x;
    if (i < n) deg[i] = 1.0f / sqrtf(deg[i]);  // deg >= 1 always
}

// ---------------- dense matmul (+bias, +relu) ----------------
// out[i][j] = act(sum_k h[i][k] * W[k][j] + b[j]); W staged in LDS.
// blockDim must be 256 and DOUT must divide 256.

template <int DIN, int DOUT, bool RELU>
__global__ void matmul_kernel(const float* __restrict__ h, const float* __restrict__ W,
                              const float* __restrict__ b, float* __restrict__ out, int n) {
    __shared__ float sW[DIN * DOUT];
    for (int idx = threadIdx.x; idx < DIN * DOUT; idx += blockDim.x) sW[idx] = W[idx];
    __syncthreads();
    const int rpb = 256 / DOUT;
    int r = blockIdx.x * rpb + threadIdx.x / DOUT;
    int j = threadIdx.x % DOUT;
    if (r >= n) return;
    float acc = b ? b[j] : 0.0f;
    const float* hr = h + (size_t)r * DIN;
#pragma unroll
    for (int k = 0; k < DIN; ++k) acc += hr[k] * sW[k * DOUT + j];
    if (RELU) acc = fmaxf(acc, 0.0f);
    out[(size_t)r * DOUT + j] = acc;
}

// ---------------- GCN aggregate ----------------

// agg[i][j] = tmp[i][j] * dinv[i]^2 + b[j]   (self-loop term + bias)
template <int DOUT>
__global__ void init_agg_kernel(const float* __restrict__ tmp, const float* __restrict__ dinv,
                                const float* __restrict__ b, float* __restrict__ agg, int n) {
    const int rpb = 256 / DOUT;
    int r = blockIdx.x * rpb + threadIdx.x / DOUT;
    int j = threadIdx.x % DOUT;
    if (r >= n) return;
    float di = dinv[r];
    agg[(size_t)r * DOUT + j] = tmp[(size_t)r * DOUT + j] * di * di + b[j];
}

// agg[dst][j] += tmp[src][j] * dinv[src]*dinv[dst]
template <int DOUT>
__global__ void scatter_kernel(const int* __restrict__ src, const int* __restrict__ dst,
                               const float* __restrict__ dinv, const float* __restrict__ tmp,
                               float* __restrict__ agg, int ne) {
    const int epb = 256 / DOUT;
    int e = blockIdx.x * epb + threadIdx.x / DOUT;
    int j = threadIdx.x % DOUT;
    if (e >= ne) return;
    int s = src[e];
    int d = dst[e];
    float nrm = dinv[s] * dinv[d];
    atomicAdd(&agg[(size_t)d * DOUT + j], tmp[(size_t)s * DOUT + j] * nrm);
}

// ---------------- LayerNorm + ReLU (one wave per row) ----------------

template <int DOUT>
__global__ void ln_relu_kernel(const float* __restrict__ t, const float* __restrict__ g,
                               const float* __restrict__ be, float* __restrict__ h, int n) {
    constexpr int PER = DOUT / 64;
    int row = blockIdx.x * (256 / 64) + (threadIdx.x >> 6);
    int lane = threadIdx.x & 63;
    if (row >= n) return;
    float v[PER];
    float s = 0.0f;
#pragma unroll
    for (int p = 0; p < PER; ++p) {
        v[p] = t[(size_t)row * DOUT + p * 64 + lane];
        s += v[p];
    }
#pragma unroll
    for (int off = 32; off; off >>= 1) s += __shfl_xor(s, off);
    float mean = s * (1.0f / DOUT);
    float q = 0.0f;
#pragma unroll
    for (int p = 0; p < PER; ++p) {
        float d = v[p] - mean;
        q += d * d;
    }
#pragma unroll
    for (int off = 32; off; off >>= 1) q += __shfl_xor(q, off);
    float inv = 1.0f / sqrtf(q * (1.0f / DOUT) + 1e-5f);
#pragma unroll
    for (int p = 0; p < PER; ++p) {
        int c = p * 64 + lane;
        float o = (v[p] - mean) * inv * g[c] + be[c];
        h[(size_t)row * DOUT + c] = fmaxf(o, 0.0f);
    }
}

// ---------------- launch ----------------

extern "C" void kernel_launch(void* const* d_in, const int* in_sizes, int n_in,
                              void* d_out, int out_size, void* d_ws, size_t ws_size,
                              hipStream_t stream) {
    const float* x   = (const float*)d_in[0];
    const int*   ei  = (const int*)d_in[1];
    const float* W0  = (const float*)d_in[2];
    const float* b0  = (const float*)d_in[3];
    const float* g0  = (const float*)d_in[4];
    const float* be0 = (const float*)d_in[5];
    const float* W1  = (const float*)d_in[6];
    const float* b1  = (const float*)d_in[7];
    const float* g1  = (const float*)d_in[8];
    const float* be1 = (const float*)d_in[9];
    const float* W2  = (const float*)d_in[10];
    const float* b2  = (const float*)d_in[11];
    const float* g2  = (const float*)d_in[12];
    const float* be2 = (const float*)d_in[13];
    const float* mW0 = (const float*)d_in[14];
    const float* mb0 = (const float*)d_in[15];
    const float* mW1 = (const float*)d_in[16];
    const float* mb1 = (const float*)d_in[17];
    const float* mW2 = (const float*)d_in[18];
    const float* mb2 = (const float*)d_in[19];
    float* out = (float*)d_out;

    const int n  = in_sizes[0] / 3;
    const int ne = in_sizes[1] / 2;
    const int* src = ei;
    const int* dst = ei + ne;

    float* ws   = (float*)d_ws;
    float* dinv = ws;                       // n floats
    float* B0   = ws + n;                   // n*128
    float* B1   = B0 + (size_t)n * 128;     // n*128
    float* B2   = B1 + (size_t)n * 128;     // n*128

    // degrees -> dinv (in place)
    init_deg_kernel<<<cdiv(n, 256), 256, 0, stream>>>(dinv, n);
    accum_deg_kernel<<<cdiv(ne, 256), 256, 0, stream>>>(dst, dinv, ne);
    dinv_kernel<<<cdiv(n, 256), 256, 0, stream>>>(dinv, n);

    // ---- GCN layer 0: 3 -> 64 ----
    matmul_kernel<3, 64, false><<<cdiv(n, 4), 256, 0, stream>>>(x, W0, nullptr, B1, n);
    init_agg_kernel<64><<<cdiv(n, 4), 256, 0, stream>>>(B1, dinv, b0, B2, n);
    scatter_kernel<64><<<cdiv(ne, 4), 256, 0, stream>>>(src, dst, dinv, B1, B2, ne);
    ln_relu_kernel<64><<<cdiv(n, 4), 256, 0, stream>>>(B2, g0, be0, B0, n);

    // ---- GCN layer 1: 64 -> 128 ----
    matmul_kernel<64, 128, false><<<cdiv(n, 2), 256, 0, stream>>>(B0, W1, nullptr, B1, n);
    init_agg_kernel<128><<<cdiv(n, 2), 256, 0, stream>>>(B1, dinv, b1, B2, n);
    scatter_kernel<128><<<cdiv(ne, 2), 256, 0, stream>>>(src, dst, dinv, B1, B2, ne);
    ln_relu_kernel<128><<<cdiv(n, 4), 256, 0, stream>>>(B2, g1, be1, B0, n);

    // ---- GCN layer 2: 128 -> 128 ----
    matmul_kernel<128, 128, false><<<cdiv(n, 2), 256, 0, stream>>>(B0, W2, nullptr, B1, n);
    init_agg_kernel<128><<<cdiv(n, 2), 256, 0, stream>>>(B1, dinv, b2, B2, n);
    scatter_kernel<128><<<cdiv(ne, 2), 256, 0, stream>>>(src, dst, dinv, B1, B2, ne);
    ln_relu_kernel<128><<<cdiv(n, 4), 256, 0, stream>>>(B2, g2, be2, B0, n);

    // ---- MLP ----
    matmul_kernel<128, 128, true><<<cdiv(n, 2), 256, 0, stream>>>(B0, mW0, mb0, B1, n);
    matmul_kernel<128, 32, true><<<cdiv(n, 8), 256, 0, stream>>>(B1, mW1, mb1, B2, n);
    matmul_kernel<32, 1, false><<<cdiv(n, 256), 256, 0, stream>>>(B2, mW2, mb2, out, n);
}